// Round 16
// baseline (565.282 us; speedup 1.0000x reference)
//
#include <hip/hip_runtime.h>

#define BS 100000
#define BQ 20000          // BS / 5
#define NWG 512           // workgroups in hist/fillA partition (1024 thr each)
#define CB  1024          // nodes per coarse bucket
#define NCMAX 512

typedef unsigned long long ull;

__device__ __forceinline__ float relu_(float v) { return fmaxf(v, 0.0f); }

// ---- 12-bit unsigned float codec (e5|m7, bias 112) ----
__device__ __forceinline__ unsigned enc12(float f) {
    unsigned u = __float_as_uint(f);
    if (u < 0x38000000u) return 0u;
    unsigned r = u - 0x38000000u;
    unsigned b = (r + 0x7FFFu + ((r >> 16) & 1u)) >> 16;
    return (b > 0xFFFu) ? 0xFFFu : b;
}
__device__ __forceinline__ float dec12(unsigned b) {
    return __uint_as_float((b << 16) + 0x38000000u);
}

// ================= binning =================
// tmp record: [dst&1023:10 @51][src:19 @32][wbits:32 @0]
// csr record (4 B): [src:19 @13][w_fix13 @0]

__global__ __launch_bounds__(1024) void hist_kernel(
    const int* __restrict__ dst, int E, int NC, int per, int* __restrict__ hist2D)
{
    __shared__ int lc[NCMAX];
    int t = threadIdx.x, g = blockIdx.x;
    for (int i = t; i < NC; i += 1024) lc[i] = 0;
    __syncthreads();
    int lo = g * per, hi = min(lo + per, E);
    if (lo < hi) {
        int nq = (hi - lo) >> 2;
        const int4* dst4 = (const int4*)(dst + lo);
        for (int q = t; q < nq; q += 1024) {
            int4 d = dst4[q];
            atomicAdd(&lc[d.x >> 10], 1);
            atomicAdd(&lc[d.y >> 10], 1);
            atomicAdd(&lc[d.z >> 10], 1);
            atomicAdd(&lc[d.w >> 10], 1);
        }
        for (int i = lo + (nq << 2) + t; i < hi; i += 1024)
            atomicAdd(&lc[dst[i] >> 10], 1);
    }
    __syncthreads();
    for (int b = t; b < NC; b += 1024) hist2D[(size_t)b * NWG + g] = lc[b];
}

__global__ __launch_bounds__(256) void reduce_kernel(
    const int* __restrict__ hist2D, int* __restrict__ bucketTot)
{
    __shared__ int s[256];
    int b = blockIdx.x, t = threadIdx.x;
    int sum = 0;
    for (int g = t; g < NWG; g += 256) sum += hist2D[(size_t)b * NWG + g];
    s[t] = sum;
    __syncthreads();
    for (int d = 128; d > 0; d >>= 1) {
        if (t < d) s[t] += s[t + d];
        __syncthreads();
    }
    if (t == 0) bucketTot[b] = s[0];
}

__global__ __launch_bounds__(512) void scanTot_kernel(
    const int* __restrict__ bucketTot, int NC, int* __restrict__ bucketBase)
{
    __shared__ int s[512];
    int t = threadIdx.x;
    int v = (t < NC) ? bucketTot[t] : 0;
    s[t] = v;
    __syncthreads();
    for (int d = 1; d < 512; d <<= 1) {
        int x = (t >= d) ? s[t - d] : 0;
        __syncthreads();
        s[t] += x;
        __syncthreads();
    }
    if (t < NC) bucketBase[t] = s[t] - v;
}

__global__ __launch_bounds__(NWG) void scanB_kernel(
    const int* __restrict__ hist2D, const int* __restrict__ bucketBase,
    int* __restrict__ wgbase)
{
    __shared__ int s[NWG];
    int b = blockIdx.x, g = threadIdx.x;
    int v = hist2D[(size_t)b * NWG + g];
    s[g] = v;
    __syncthreads();
    for (int d = 1; d < NWG; d <<= 1) {
        int x = (g >= d) ? s[g - d] : 0;
        __syncthreads();
        s[g] += x;
        __syncthreads();
    }
    wgbase[(size_t)b * NWG + g] = bucketBase[b] + s[g] - v;
}

__device__ __forceinline__ void fillA_one(int d, int s, float wv,
    int* cur, ull* __restrict__ tmp)
{
    int b = d >> 10;
    int pos = atomicAdd(&cur[b], 1);
    ull rec = (ull)__float_as_uint(wv)
            | ((ull)(unsigned int)s << 32)
            | ((ull)(unsigned int)(d & (CB - 1)) << 51);
    tmp[pos] = rec;
}

__global__ __launch_bounds__(1024) void fillA_kernel(
    const int* __restrict__ src, const int* __restrict__ dst,
    const float* __restrict__ w, int E, int NC, int per,
    const int* __restrict__ wgbase, ull* __restrict__ tmp)
{
    __shared__ int cur[NCMAX];
    int t = threadIdx.x, g = blockIdx.x;
    for (int i = t; i < NC; i += 1024) cur[i] = wgbase[(size_t)i * NWG + g];
    __syncthreads();
    int lo = g * per, hi = min(lo + per, E);
    if (lo >= hi) return;
    int nq = (hi - lo) >> 2;
    const int4* src4 = (const int4*)(src + lo);
    const int4* dst4 = (const int4*)(dst + lo);
    const float4* w4 = (const float4*)(w + lo);
    for (int q = t; q < nq; q += 1024) {
        int4 d = dst4[q];
        int4 s = src4[q];
        float4 wv = w4[q];
        fillA_one(d.x, s.x, wv.x, cur, tmp);
        fillA_one(d.y, s.y, wv.y, cur, tmp);
        fillA_one(d.z, s.z, wv.z, cur, tmp);
        fillA_one(d.w, s.w, wv.w, cur, tmp);
    }
    for (int i = lo + (nq << 2) + t; i < hi; i += 1024)
        fillA_one(dst[i], src[i], w[i], cur, tmp);
}

// one WG (1024 thr) per bucket (1024 nodes, ~16K edges):
// count -> scan(1024) -> 4-B csr scatter
__global__ __launch_bounds__(1024) void fillA2B_kernel(
    const ull* __restrict__ tmp, const int* __restrict__ wgbase,
    int NC, int N, int E,
    unsigned* __restrict__ csr, int* __restrict__ offsets)
{
    __shared__ int cnt[CB];
    __shared__ int ssum[1024];
    int b = blockIdx.x, t = threadIdx.x;
    int lo = wgbase[(size_t)b * NWG];
    int hi = (b == NC - 1) ? E : wgbase[(size_t)(b + 1) * NWG];
    int M = hi - lo;

    cnt[t] = 0;
    __syncthreads();
    {
        int k = t;
        for (; k + 1024 < M; k += 2048) {
            ull r0 = tmp[lo + k];
            ull r1 = tmp[lo + k + 1024];
            atomicAdd(&cnt[(int)(r0 >> 51)], 1);
            atomicAdd(&cnt[(int)(r1 >> 51)], 1);
        }
        if (k < M) atomicAdd(&cnt[(int)(tmp[lo + k] >> 51)], 1);
    }
    __syncthreads();

    int v = cnt[t];
    ssum[t] = v;
    __syncthreads();
    for (int d = 1; d < 1024; d <<= 1) {
        int x = (t >= d) ? ssum[t - d] : 0;
        __syncthreads();
        ssum[t] += x;
        __syncthreads();
    }
    int excl = ssum[t] - v;

    int node = b * CB + t;
    if (node < N) offsets[node] = lo + excl;
    if (b == NC - 1 && t == 0) offsets[N] = E;
    __syncthreads();
    cnt[t] = excl;
    __syncthreads();

    for (int e = lo + t; e < hi; e += 1024) {
        ull rec = tmp[e];
        int dl = (int)(rec >> 51);
        int pos = atomicAdd(&cnt[dl], 1);
        float w = __uint_as_float((unsigned int)(rec & 0xFFFFFFFFull));
        unsigned wq = (unsigned)fmaf(w, 8191.0f, 0.5f);
        unsigned sidx = (unsigned)((rec >> 32) & 0x7FFFFull);
        csr[lo + pos] = (sidx << 13) | wq;
    }
}

// ---------------- z1 = relu(x @ Wl + bl) -> 12-bit packed rows ----------------
__global__ __launch_bounds__(256) void z1_kernel(
    const float* __restrict__ in,
    const float* __restrict__ we, const float* __restrict__ be,
    const float* __restrict__ wt, const float* __restrict__ bt,
    unsigned* __restrict__ zq, int n)
{
    __shared__ float sWe[32 * 32];
    __shared__ float sWt[32 * 8];
    __shared__ float sBe[32];
    __shared__ float sBt[8];
    for (int i = threadIdx.x; i < 32 * 32; i += 256) sWe[i] = we[i];
    for (int i = threadIdx.x; i < 32 * 8; i += 256) sWt[i] = wt[i];
    if (threadIdx.x < 32) sBe[threadIdx.x] = be[threadIdx.x];
    if (threadIdx.x < 8)  sBt[threadIdx.x] = bt[threadIdx.x];
    __syncthreads();

    int node = blockIdx.x * 256 + threadIdx.x;
    if (node >= n) return;

    float row[32];
    {
        const float4* rp = (const float4*)(in + (size_t)node * 32);
        #pragma unroll
        for (int q = 0; q < 8; q++) {
            float4 v = rp[q];
            row[4*q] = v.x; row[4*q+1] = v.y; row[4*q+2] = v.z; row[4*q+3] = v.w;
        }
    }

    float o[40];
    #pragma unroll
    for (int j = 0; j < 32; j++) o[j] = sBe[j];
    #pragma unroll
    for (int i = 0; i < 32; i++) {
        float v = row[i];
        #pragma unroll
        for (int j = 0; j < 32; j++) o[j] = fmaf(v, sWe[i * 32 + j], o[j]);
    }
    #pragma unroll
    for (int j = 0; j < 8; j++) o[32 + j] = sBt[j];
    #pragma unroll
    for (int i = 0; i < 32; i++) {
        float v = row[i];
        #pragma unroll
        for (int j = 0; j < 8; j++) o[32 + j] = fmaf(v, sWt[i * 8 + j], o[32 + j]);
    }

    unsigned b[40];
    #pragma unroll
    for (int i = 0; i < 40; i++) b[i] = enc12(relu_(o[i]));
    unsigned wd[16];
    #pragma unroll
    for (int k = 0; k < 5; k++) {
        wd[3*k+0] = b[8*k+0] | (b[8*k+1] << 12) | (b[8*k+2] << 24);
        wd[3*k+1] = (b[8*k+2] >> 8) | (b[8*k+3] << 4) | (b[8*k+4] << 16) | (b[8*k+5] << 28);
        wd[3*k+2] = (b[8*k+5] >> 4) | (b[8*k+6] << 8) | (b[8*k+7] << 20);
    }
    wd[15] = 0;
    uint4* zv = (uint4*)(zq + (size_t)node * 16);
    #pragma unroll
    for (int q = 0; q < 4; q++)
        zv[q] = make_uint4(wd[4*q], wd[4*q+1], wd[4*q+2], wd[4*q+3]);
}

// ---------------- decode+accumulate one edge ----------------
__device__ __forceinline__ void acc_edge(float* acc, float w,
    const uint4& A, const uint4& B, const uint4& C, const uint4& D)
{
    unsigned wds[15] = {A.x, A.y, A.z, A.w, B.x, B.y, B.z, B.w,
                        C.x, C.y, C.z, C.w, D.x, D.y, D.z};
    #pragma unroll
    for (int k = 0; k < 5; k++) {
        unsigned xw = wds[3*k+0], yw = wds[3*k+1], zw = wds[3*k+2];
        acc[8*k+0] = fmaf(w, dec12(xw & 0xFFFu),                       acc[8*k+0]);
        acc[8*k+1] = fmaf(w, dec12((xw >> 12) & 0xFFFu),               acc[8*k+1]);
        acc[8*k+2] = fmaf(w, dec12(((xw >> 24) | (yw << 8)) & 0xFFFu), acc[8*k+2]);
        acc[8*k+3] = fmaf(w, dec12((yw >> 4) & 0xFFFu),                acc[8*k+3]);
        acc[8*k+4] = fmaf(w, dec12((yw >> 16) & 0xFFFu),               acc[8*k+4]);
        acc[8*k+5] = fmaf(w, dec12(((yw >> 28) | (zw << 4)) & 0xFFFu), acc[8*k+5]);
        acc[8*k+6] = fmaf(w, dec12((zw >> 8) & 0xFFFu),                acc[8*k+6]);
        acc[8*k+7] = fmaf(w, dec12((zw >> 20) & 0xFFFu),               acc[8*k+7]);
    }
}

// ---------------- fused aggregate + finalize (+ optional fused z2 emit) ----------------
template <int RW, int TIN, int TOFF, bool EMITZ>
__global__ __launch_bounds__(256) void fin_kernel(
    const float* __restrict__ in,
    const unsigned* __restrict__ zq,
    const int* __restrict__ offsets,
    const unsigned* __restrict__ csr,        // 4-B records [src:19 @13][w13 @0]
    const float* __restrict__ wre, const float* __restrict__ bre,
    const float* __restrict__ wrt, const float* __restrict__ brt,
    const float* __restrict__ w2e, const float* __restrict__ b2e,
    const float* __restrict__ w2t, const float* __restrict__ b2t,
    float* __restrict__ outbuf, int nOut,
    unsigned* __restrict__ zq2,
    int n)
{
    __shared__ float sWe[64 * 32];
    __shared__ float sWt[(TIN + 8) * 8];
    __shared__ float sBe[32];
    __shared__ float sBt[8];
    __shared__ float sW2e[32 * 32];
    __shared__ float sW2t[8 * 8];
    __shared__ float sB2e[32];
    __shared__ float sB2t[8];
    for (int i = threadIdx.x; i < 64 * 32; i += 256) sWe[i] = wre[i];
    for (int i = threadIdx.x; i < (TIN + 8) * 8; i += 256) sWt[i] = wrt[i];
    if (threadIdx.x < 32) sBe[threadIdx.x] = bre[threadIdx.x];
    if (threadIdx.x < 8)  sBt[threadIdx.x] = brt[threadIdx.x];
    if (EMITZ) {
        for (int i = threadIdx.x; i < 32 * 32; i += 256) sW2e[i] = w2e[i];
        for (int i = threadIdx.x; i < 8 * 8; i += 256) sW2t[i] = w2t[i];
        if (threadIdx.x < 32) sB2e[threadIdx.x] = b2e[threadIdx.x];
        if (threadIdx.x < 8)  sB2t[threadIdx.x] = b2t[threadIdx.x];
    }
    __syncthreads();

    int node = blockIdx.x * 256 + threadIdx.x;
    if (node >= n) return;

    float acc[40];
    #pragma unroll
    for (int j = 0; j < 40; j++) acc[j] = 0.0f;
    float wsum = 1.0f;

    const float DW = 1.0f / 8191.0f;
    int e0 = offsets[node];
    int e1 = offsets[node + 1];
    int e = e0;
    for (; e + 2 <= e1; e += 2) {
        unsigned pk0 = csr[e];
        unsigned pk1 = csr[e + 1];
        const uint4* p0 = (const uint4*)(zq + (size_t)(pk0 >> 13) * 16);
        const uint4* p1 = (const uint4*)(zq + (size_t)(pk1 >> 13) * 16);
        uint4 A0 = p0[0], B0 = p0[1], C0 = p0[2], D0 = p0[3];
        uint4 A1 = p1[0], B1 = p1[1], C1 = p1[2], D1 = p1[3];
        float w0 = (float)(pk0 & 8191u) * DW;
        float w1 = (float)(pk1 & 8191u) * DW;
        acc_edge(acc, w0, A0, B0, C0, D0);
        acc_edge(acc, w1, A1, B1, C1, D1);
        wsum += w0;
        wsum += w1;
    }
    if (e < e1) {
        unsigned pk = csr[e];
        const uint4* zp = (const uint4*)(zq + (size_t)(pk >> 13) * 16);
        uint4 A = zp[0], B = zp[1], C = zp[2], D = zp[3];
        float w = (float)(pk & 8191u) * DW;
        acc_edge(acc, w, A, B, C, D);
        wsum += w;
    }
    float inv = 1.0f / wsum;
    #pragma unroll
    for (int j = 0; j < 40; j++) acc[j] *= inv;

    float row[RW];
    {
        const float4* rp = (const float4*)(in + (size_t)node * RW);
        #pragma unroll
        for (int q = 0; q < RW / 4; q++) {
            float4 v = rp[q];
            row[4*q] = v.x; row[4*q+1] = v.y; row[4*q+2] = v.z; row[4*q+3] = v.w;
        }
    }

    float h[40];

    {
        float o[32];
        #pragma unroll
        for (int j = 0; j < 32; j++) o[j] = sBe[j];
        #pragma unroll
        for (int i = 0; i < 32; i++) {
            float v = row[i];
            #pragma unroll
            for (int j = 0; j < 32; j++) o[j] = fmaf(v, sWe[i * 32 + j], o[j]);
        }
        #pragma unroll
        for (int i = 0; i < 32; i++) {
            float v = acc[i];
            #pragma unroll
            for (int j = 0; j < 32; j++) o[j] = fmaf(v, sWe[(32 + i) * 32 + j], o[j]);
        }
        #pragma unroll
        for (int j = 0; j < 32; j++) h[j] = relu_(o[j]);
    }
    {
        float ot[8];
        #pragma unroll
        for (int j = 0; j < 8; j++) ot[j] = sBt[j];
        #pragma unroll
        for (int i = 0; i < TIN; i++) {
            float v = row[TOFF + i];
            #pragma unroll
            for (int j = 0; j < 8; j++) ot[j] = fmaf(v, sWt[i * 8 + j], ot[j]);
        }
        #pragma unroll
        for (int i = 0; i < 8; i++) {
            float v = acc[32 + i];
            #pragma unroll
            for (int j = 0; j < 8; j++) ot[j] = fmaf(v, sWt[(TIN + i) * 8 + j], ot[j]);
        }
        #pragma unroll
        for (int j = 0; j < 8; j++) h[32 + j] = relu_(ot[j]);
    }

    if (node < nOut) {
        float4* ov = (float4*)(outbuf + (size_t)node * 40);
        #pragma unroll
        for (int q = 0; q < 10; q++)
            ov[q] = make_float4(h[4*q], h[4*q+1], h[4*q+2], h[4*q+3]);
    }

    if (EMITZ) {
        float z2[40];
        #pragma unroll
        for (int j = 0; j < 32; j++) z2[j] = sB2e[j];
        #pragma unroll
        for (int i = 0; i < 32; i++) {
            float v = h[i];
            #pragma unroll
            for (int j = 0; j < 32; j++) z2[j] = fmaf(v, sW2e[i * 32 + j], z2[j]);
        }
        #pragma unroll
        for (int j = 0; j < 8; j++) z2[32 + j] = sB2t[j];
        #pragma unroll
        for (int i = 0; i < 8; i++) {
            float v = h[32 + i];
            #pragma unroll
            for (int j = 0; j < 8; j++) z2[32 + j] = fmaf(v, sW2t[i * 8 + j], z2[32 + j]);
        }
        unsigned b[40];
        #pragma unroll
        for (int i = 0; i < 40; i++) b[i] = enc12(relu_(z2[i]));
        unsigned wd[16];
        #pragma unroll
        for (int k = 0; k < 5; k++) {
            wd[3*k+0] = b[8*k+0] | (b[8*k+1] << 12) | (b[8*k+2] << 24);
            wd[3*k+1] = (b[8*k+2] >> 8) | (b[8*k+3] << 4) | (b[8*k+4] << 16) | (b[8*k+5] << 28);
            wd[3*k+2] = (b[8*k+5] >> 4) | (b[8*k+6] << 8) | (b[8*k+7] << 20);
        }
        wd[15] = 0;
        uint4* zv = (uint4*)(zq2 + (size_t)node * 16);
        #pragma unroll
        for (int q = 0; q < 4; q++)
            zv[q] = make_uint4(wd[4*q], wd[4*q+1], wd[4*q+2], wd[4*q+3]);
    }
}

// ---------------- loss ----------------

__device__ __forceinline__ void load40(const float* p, float* r) {
    const float4* v = (const float4*)p;
    #pragma unroll
    for (int q = 0; q < 10; q++) {
        float4 t = v[q];
        r[4*q] = t.x; r[4*q+1] = t.y; r[4*q+2] = t.z; r[4*q+3] = t.w;
    }
}

__device__ __forceinline__ float dot40(const float* a, const float* b) {
    float s = 0.0f;
    #pragma unroll
    for (int d = 0; d < 40; d++) s = fmaf(a[d], b[d], s);
    return s;
}

__device__ __forceinline__ void softmax5(const float l[5], float q[5]) {
    float m = l[0];
    #pragma unroll
    for (int c = 1; c < 5; c++) m = fmaxf(m, l[c]);
    float s = 0.0f;
    #pragma unroll
    for (int c = 0; c < 5; c++) { q[c] = expf(l[c] - m); s += q[c]; }
    float inv = 1.0f / s;
    #pragma unroll
    for (int c = 0; c < 5; c++) q[c] *= inv;
}

__device__ __forceinline__ float ent5(const float q[5]) {
    float e = 0.0f;
    #pragma unroll
    for (int c = 0; c < 5; c++) e += q[c] * logf(q[c] + 1e-20f);
    return e;
}

__device__ __forceinline__ float dot5(const float* a, const float* b) {
    float s = 0.0f;
    #pragma unroll
    for (int c = 0; c < 5; c++) s += a[c] * b[c];
    return s;
}

__global__ __launch_bounds__(256) void loss_kernel(
    const float* __restrict__ emb,
    const float* __restrict__ cent,
    const float* __restrict__ cent_t,
    float* __restrict__ out)
{
    __shared__ float sC[5 * 40];
    for (int i = threadIdx.x; i < 200; i += 256) {
        int c = i / 40, d = i % 40;
        sC[i] = (d < 32) ? cent[c * 32 + d] : cent_t[c * 8 + (d - 32)];
    }
    __syncthreads();

    int i = blockIdx.x * 256 + threadIdx.x;
    float contrib = 0.0f;
    if (i < BQ) {
        const float* base = emb + (size_t)i * 200;

        float ctr[40];
        load40(base, ctr);
        float l[5];
        #pragma unroll
        for (int c = 0; c < 5; c++) l[c] = dot40(ctr, sC + c * 40);
        float qc[5];
        softmax5(l, qc);
        float ent = ent5(qc);

        float rowv[40];
        load40(base + 40, rowv);
        float pd = dot40(ctr, rowv);
        #pragma unroll
        for (int c = 0; c < 5; c++) l[c] = dot40(rowv, sC + c * 40);
        float qp[5];
        softmax5(l, qp);
        float cpd = dot5(qc, qp);
        ent += ent5(qp);

        float nd = -1e30f, cnd = -1e30f;
        #pragma unroll
        for (int k = 0; k < 3; k++) {
            load40(base + (2 + k) * 40, rowv);
            nd = fmaxf(nd, dot40(ctr, rowv));
            #pragma unroll
            for (int c = 0; c < 5; c++) l[c] = dot40(rowv, sC + c * 40);
            float qn[5];
            softmax5(l, qn);
            cnd = fmaxf(cnd, dot5(qc, qn));
            ent += ent5(qn);
        }

        float mm  = fmaxf(nd - pd + 1.0f, 0.0f);
        float cmm = fmaxf(cnd - cpd + 1.0f, 0.0f);
        contrib = (mm + cmm) * (1.0f / (float)BQ) + 0.01f * (1.0f / (float)BS) * ent;
    }

    #pragma unroll
    for (int off = 32; off > 0; off >>= 1) contrib += __shfl_down(contrib, off);
    if ((threadIdx.x & 63) == 0) atomicAdd(out, contrib);
}

// ---------------- launch ----------------

extern "C" void kernel_launch(void* const* d_in, const int* in_sizes, int n_in,
                              void* d_out, int out_size, void* d_ws, size_t ws_size,
                              hipStream_t stream) {
    const float* x      = (const float*)d_in[0];
    const float* weight = (const float*)d_in[1];
    const float* e_w1l  = (const float*)d_in[2];
    const float* e_b1l  = (const float*)d_in[3];
    const float* e_w1r  = (const float*)d_in[4];
    const float* e_b1r  = (const float*)d_in[5];
    const float* e_w2l  = (const float*)d_in[6];
    const float* e_b2l  = (const float*)d_in[7];
    const float* e_w2r  = (const float*)d_in[8];
    const float* e_b2r  = (const float*)d_in[9];
    const float* t_w1l  = (const float*)d_in[10];
    const float* t_b1l  = (const float*)d_in[11];
    const float* t_w1r  = (const float*)d_in[12];
    const float* t_b1r  = (const float*)d_in[13];
    const float* t_w2l  = (const float*)d_in[14];
    const float* t_b2l  = (const float*)d_in[15];
    const float* t_w2r  = (const float*)d_in[16];
    const float* t_b2r  = (const float*)d_in[17];
    const float* cent   = (const float*)d_in[18];
    const float* cent_t = (const float*)d_in[19];
    const int*   eidx   = (const int*)d_in[20];

    const int E = in_sizes[20] / 2;
    const int N = in_sizes[0] / 32;
    const int* srcI = eidx;
    const int* dstI = eidx + E;
    float* out = (float*)d_out;

    const int NC = (N + CB - 1) / CB;                    // 489 buckets (1024 nodes)
    const int per = (((E + NWG - 1) / NWG) + 3) & ~3;    // WG slice, multiple of 4

    char* p = (char*)d_ws;
    auto alloc = [&](size_t bytes) -> char* {
        char* r = p;
        p += (bytes + 255) & ~(size_t)255;
        return r;
    };
    char* regionA = alloc((size_t)E * 8);                // tmp (64 MB) / zq1 (32 MB)
    ull*  tmp     = (ull*)regionA;
    unsigned* zq1 = (unsigned*)regionA;
    unsigned* zq2 = (unsigned*)alloc((size_t)N * 64);    // 32 MB
    float* hcat   = (float*)alloc((size_t)BS * 40 * 4);  // 16 MB
    float* emb    = (float*)alloc((size_t)BS * 40 * 4);  // 16 MB
    unsigned* csr = (unsigned*)alloc((size_t)E * 4);     // 32 MB
    int*   offsets= (int*)alloc((size_t)(N + 1) * 4);
    int*   hist2D = (int*)alloc((size_t)NC * NWG * 4);   // 1 MB
    int*   wgbase = (int*)alloc((size_t)NC * NWG * 4);   // 1 MB
    int*   bucketTot  = (int*)alloc((size_t)NC * 4);
    int*   bucketBase = (int*)alloc((size_t)NC * 4);
    (void)ws_size;

    hipMemsetAsync(d_out, 0, sizeof(float), stream);

    // binning
    hist_kernel<<<NWG, 1024, 0, stream>>>(dstI, E, NC, per, hist2D);
    reduce_kernel<<<NC, 256, 0, stream>>>(hist2D, bucketTot);
    scanTot_kernel<<<1, 512, 0, stream>>>(bucketTot, NC, bucketBase);
    scanB_kernel<<<NC, NWG, 0, stream>>>(hist2D, bucketBase, wgbase);
    fillA_kernel<<<NWG, 1024, 0, stream>>>(srcI, dstI, weight, E, NC, per, wgbase, tmp);
    fillA2B_kernel<<<NC, 1024, 0, stream>>>(tmp, wgbase, NC, N, E, csr, offsets);

    const int nb = (N + 255) / 256;
    z1_kernel<<<nb, 256, 0, stream>>>(x, e_w1l, e_b1l, t_w1l, t_b1l, zq1, N);
    fin_kernel<32, 32, 0, true><<<nb, 256, 0, stream>>>(
        x, zq1, offsets, csr,
        e_w1r, e_b1r, t_w1r, t_b1r,
        e_w2l, e_b2l, t_w2l, t_b2l,
        hcat, BS, zq2, N);
    const int nb2 = (BS + 255) / 256;
    fin_kernel<40, 8, 32, false><<<nb2, 256, 0, stream>>>(
        hcat, zq2, offsets, csr,
        e_w2r, e_b2r, t_w2r, t_b2r,
        nullptr, nullptr, nullptr, nullptr,
        emb, BS, nullptr, BS);

    loss_kernel<<<(BQ + 255) / 256, 256, 0, stream>>>(emb, cent, cent_t, out);
}

// Round 17
// 506.520 us; speedup vs baseline: 1.1160x; 1.1160x over previous
//
#include <hip/hip_runtime.h>

#define BS 100000
#define BQ 20000          // BS / 5
#define NWG 512           // workgroups in hist/fillA partition (1024 thr each)
#define CB  1024          // nodes per coarse bucket
#define NCMAX 512
#define CAP 17408         // staged 4-B records in fillA2B (mean ~16380, +8 sigma)

typedef unsigned long long ull;

__device__ __forceinline__ float relu_(float v) { return fmaxf(v, 0.0f); }

// ---- 12-bit unsigned float codec (e5|m7, bias 112) ----
__device__ __forceinline__ unsigned enc12(float f) {
    unsigned u = __float_as_uint(f);
    if (u < 0x38000000u) return 0u;
    unsigned r = u - 0x38000000u;
    unsigned b = (r + 0x7FFFu + ((r >> 16) & 1u)) >> 16;
    return (b > 0xFFFu) ? 0xFFFu : b;
}
__device__ __forceinline__ float dec12(unsigned b) {
    return __uint_as_float((b << 16) + 0x38000000u);
}

// ================= binning =================
// tmp record: [dst&1023:10 @51][src:19 @32][wbits:32 @0]
// csr record (4 B): [src:19 @13][w_fix13 @0]

__global__ __launch_bounds__(1024) void hist_kernel(
    const int* __restrict__ dst, int E, int NC, int per, int* __restrict__ hist2D)
{
    __shared__ int lc[NCMAX];
    int t = threadIdx.x, g = blockIdx.x;
    for (int i = t; i < NC; i += 1024) lc[i] = 0;
    __syncthreads();
    int lo = g * per, hi = min(lo + per, E);
    if (lo < hi) {
        int nq = (hi - lo) >> 2;
        const int4* dst4 = (const int4*)(dst + lo);
        for (int q = t; q < nq; q += 1024) {
            int4 d = dst4[q];
            atomicAdd(&lc[d.x >> 10], 1);
            atomicAdd(&lc[d.y >> 10], 1);
            atomicAdd(&lc[d.z >> 10], 1);
            atomicAdd(&lc[d.w >> 10], 1);
        }
        for (int i = lo + (nq << 2) + t; i < hi; i += 1024)
            atomicAdd(&lc[dst[i] >> 10], 1);
    }
    __syncthreads();
    for (int b = t; b < NC; b += 1024) hist2D[(size_t)b * NWG + g] = lc[b];
}

__global__ __launch_bounds__(256) void reduce_kernel(
    const int* __restrict__ hist2D, int* __restrict__ bucketTot)
{
    __shared__ int s[256];
    int b = blockIdx.x, t = threadIdx.x;
    int sum = 0;
    for (int g = t; g < NWG; g += 256) sum += hist2D[(size_t)b * NWG + g];
    s[t] = sum;
    __syncthreads();
    for (int d = 128; d > 0; d >>= 1) {
        if (t < d) s[t] += s[t + d];
        __syncthreads();
    }
    if (t == 0) bucketTot[b] = s[0];
}

__global__ __launch_bounds__(512) void scanTot_kernel(
    const int* __restrict__ bucketTot, int NC, int* __restrict__ bucketBase)
{
    __shared__ int s[512];
    int t = threadIdx.x;
    int v = (t < NC) ? bucketTot[t] : 0;
    s[t] = v;
    __syncthreads();
    for (int d = 1; d < 512; d <<= 1) {
        int x = (t >= d) ? s[t - d] : 0;
        __syncthreads();
        s[t] += x;
        __syncthreads();
    }
    if (t < NC) bucketBase[t] = s[t] - v;
}

__global__ __launch_bounds__(NWG) void scanB_kernel(
    const int* __restrict__ hist2D, const int* __restrict__ bucketBase,
    int* __restrict__ wgbase)
{
    __shared__ int s[NWG];
    int b = blockIdx.x, g = threadIdx.x;
    int v = hist2D[(size_t)b * NWG + g];
    s[g] = v;
    __syncthreads();
    for (int d = 1; d < NWG; d <<= 1) {
        int x = (g >= d) ? s[g - d] : 0;
        __syncthreads();
        s[g] += x;
        __syncthreads();
    }
    wgbase[(size_t)b * NWG + g] = bucketBase[b] + s[g] - v;
}

__device__ __forceinline__ void fillA_one(int d, int s, float wv,
    int* cur, ull* __restrict__ tmp)
{
    int b = d >> 10;
    int pos = atomicAdd(&cur[b], 1);
    ull rec = (ull)__float_as_uint(wv)
            | ((ull)(unsigned int)s << 32)
            | ((ull)(unsigned int)(d & (CB - 1)) << 51);
    tmp[pos] = rec;
}

__global__ __launch_bounds__(1024) void fillA_kernel(
    const int* __restrict__ src, const int* __restrict__ dst,
    const float* __restrict__ w, int E, int NC, int per,
    const int* __restrict__ wgbase, ull* __restrict__ tmp)
{
    __shared__ int cur[NCMAX];
    int t = threadIdx.x, g = blockIdx.x;
    for (int i = t; i < NC; i += 1024) cur[i] = wgbase[(size_t)i * NWG + g];
    __syncthreads();
    int lo = g * per, hi = min(lo + per, E);
    if (lo >= hi) return;
    int nq = (hi - lo) >> 2;
    const int4* src4 = (const int4*)(src + lo);
    const int4* dst4 = (const int4*)(dst + lo);
    const float4* w4 = (const float4*)(w + lo);
    for (int q = t; q < nq; q += 1024) {
        int4 d = dst4[q];
        int4 s = src4[q];
        float4 wv = w4[q];
        fillA_one(d.x, s.x, wv.x, cur, tmp);
        fillA_one(d.y, s.y, wv.y, cur, tmp);
        fillA_one(d.z, s.z, wv.z, cur, tmp);
        fillA_one(d.w, s.w, wv.w, cur, tmp);
    }
    for (int i = lo + (nq << 2) + t; i < hi; i += 1024)
        fillA_one(dst[i], src[i], w[i], cur, tmp);
}

// one WG (1024 thr) per bucket: count -> scan(1024) -> LDS-staged reorder ->
// sequential full-line csr write (kills the 8M scattered 4-B transactions)
__global__ __launch_bounds__(1024) void fillA2B_kernel(
    const ull* __restrict__ tmp, const int* __restrict__ wgbase,
    int NC, int N, int E,
    unsigned* __restrict__ csr, int* __restrict__ offsets)
{
    __shared__ int cnt[CB];
    __shared__ int ssum[1024];
    extern __shared__ unsigned recs[];   // CAP 4-B records
    int b = blockIdx.x, t = threadIdx.x;
    int lo = wgbase[(size_t)b * NWG];
    int hi = (b == NC - 1) ? E : wgbase[(size_t)(b + 1) * NWG];
    int M = hi - lo;

    cnt[t] = 0;
    __syncthreads();
    {
        int k = t;
        for (; k + 1024 < M; k += 2048) {
            ull r0 = tmp[lo + k];
            ull r1 = tmp[lo + k + 1024];
            atomicAdd(&cnt[(int)(r0 >> 51)], 1);
            atomicAdd(&cnt[(int)(r1 >> 51)], 1);
        }
        if (k < M) atomicAdd(&cnt[(int)(tmp[lo + k] >> 51)], 1);
    }
    __syncthreads();

    int v = cnt[t];
    ssum[t] = v;
    __syncthreads();
    for (int d = 1; d < 1024; d <<= 1) {
        int x = (t >= d) ? ssum[t - d] : 0;
        __syncthreads();
        ssum[t] += x;
        __syncthreads();
    }
    int excl = ssum[t] - v;

    int node = b * CB + t;
    if (node < N) offsets[node] = lo + excl;
    if (b == NC - 1 && t == 0) offsets[N] = E;
    __syncthreads();
    cnt[t] = excl;
    __syncthreads();

    if (M <= CAP) {
        // reorder into LDS (scatter absorbed by LDS), then stream out sequentially
        for (int e = lo + t; e < hi; e += 1024) {
            ull rec = tmp[e];
            int dl = (int)(rec >> 51);
            int pos = atomicAdd(&cnt[dl], 1);
            float w = __uint_as_float((unsigned int)(rec & 0xFFFFFFFFull));
            unsigned wq = (unsigned)fmaf(w, 8191.0f, 0.5f);
            unsigned sidx = (unsigned)((rec >> 32) & 0x7FFFFull);
            recs[pos] = (sidx << 13) | wq;
        }
        __syncthreads();
        for (int i = t; i < M; i += 1024)
            csr[lo + i] = recs[i];
    } else {
        // fallback: direct scatter within the bucket's csr window
        for (int e = lo + t; e < hi; e += 1024) {
            ull rec = tmp[e];
            int dl = (int)(rec >> 51);
            int pos = atomicAdd(&cnt[dl], 1);
            float w = __uint_as_float((unsigned int)(rec & 0xFFFFFFFFull));
            unsigned wq = (unsigned)fmaf(w, 8191.0f, 0.5f);
            unsigned sidx = (unsigned)((rec >> 32) & 0x7FFFFull);
            csr[lo + pos] = (sidx << 13) | wq;
        }
    }
}

// ---------------- z1 = relu(x @ Wl + bl) -> 12-bit packed rows ----------------
__global__ __launch_bounds__(256) void z1_kernel(
    const float* __restrict__ in,
    const float* __restrict__ we, const float* __restrict__ be,
    const float* __restrict__ wt, const float* __restrict__ bt,
    unsigned* __restrict__ zq, int n)
{
    __shared__ float sWe[32 * 32];
    __shared__ float sWt[32 * 8];
    __shared__ float sBe[32];
    __shared__ float sBt[8];
    for (int i = threadIdx.x; i < 32 * 32; i += 256) sWe[i] = we[i];
    for (int i = threadIdx.x; i < 32 * 8; i += 256) sWt[i] = wt[i];
    if (threadIdx.x < 32) sBe[threadIdx.x] = be[threadIdx.x];
    if (threadIdx.x < 8)  sBt[threadIdx.x] = bt[threadIdx.x];
    __syncthreads();

    int node = blockIdx.x * 256 + threadIdx.x;
    if (node >= n) return;

    float row[32];
    {
        const float4* rp = (const float4*)(in + (size_t)node * 32);
        #pragma unroll
        for (int q = 0; q < 8; q++) {
            float4 v = rp[q];
            row[4*q] = v.x; row[4*q+1] = v.y; row[4*q+2] = v.z; row[4*q+3] = v.w;
        }
    }

    float o[40];
    #pragma unroll
    for (int j = 0; j < 32; j++) o[j] = sBe[j];
    #pragma unroll
    for (int i = 0; i < 32; i++) {
        float v = row[i];
        #pragma unroll
        for (int j = 0; j < 32; j++) o[j] = fmaf(v, sWe[i * 32 + j], o[j]);
    }
    #pragma unroll
    for (int j = 0; j < 8; j++) o[32 + j] = sBt[j];
    #pragma unroll
    for (int i = 0; i < 32; i++) {
        float v = row[i];
        #pragma unroll
        for (int j = 0; j < 8; j++) o[32 + j] = fmaf(v, sWt[i * 8 + j], o[32 + j]);
    }

    unsigned b[40];
    #pragma unroll
    for (int i = 0; i < 40; i++) b[i] = enc12(relu_(o[i]));
    unsigned wd[16];
    #pragma unroll
    for (int k = 0; k < 5; k++) {
        wd[3*k+0] = b[8*k+0] | (b[8*k+1] << 12) | (b[8*k+2] << 24);
        wd[3*k+1] = (b[8*k+2] >> 8) | (b[8*k+3] << 4) | (b[8*k+4] << 16) | (b[8*k+5] << 28);
        wd[3*k+2] = (b[8*k+5] >> 4) | (b[8*k+6] << 8) | (b[8*k+7] << 20);
    }
    wd[15] = 0;
    uint4* zv = (uint4*)(zq + (size_t)node * 16);
    #pragma unroll
    for (int q = 0; q < 4; q++)
        zv[q] = make_uint4(wd[4*q], wd[4*q+1], wd[4*q+2], wd[4*q+3]);
}

// ---------------- decode+accumulate one edge ----------------
__device__ __forceinline__ void acc_edge(float* acc, float w,
    const uint4& A, const uint4& B, const uint4& C, const uint4& D)
{
    unsigned wds[15] = {A.x, A.y, A.z, A.w, B.x, B.y, B.z, B.w,
                        C.x, C.y, C.z, C.w, D.x, D.y, D.z};
    #pragma unroll
    for (int k = 0; k < 5; k++) {
        unsigned xw = wds[3*k+0], yw = wds[3*k+1], zw = wds[3*k+2];
        acc[8*k+0] = fmaf(w, dec12(xw & 0xFFFu),                       acc[8*k+0]);
        acc[8*k+1] = fmaf(w, dec12((xw >> 12) & 0xFFFu),               acc[8*k+1]);
        acc[8*k+2] = fmaf(w, dec12(((xw >> 24) | (yw << 8)) & 0xFFFu), acc[8*k+2]);
        acc[8*k+3] = fmaf(w, dec12((yw >> 4) & 0xFFFu),                acc[8*k+3]);
        acc[8*k+4] = fmaf(w, dec12((yw >> 16) & 0xFFFu),               acc[8*k+4]);
        acc[8*k+5] = fmaf(w, dec12(((yw >> 28) | (zw << 4)) & 0xFFFu), acc[8*k+5]);
        acc[8*k+6] = fmaf(w, dec12((zw >> 8) & 0xFFFu),                acc[8*k+6]);
        acc[8*k+7] = fmaf(w, dec12((zw >> 20) & 0xFFFu),               acc[8*k+7]);
    }
}

// ---------------- fused aggregate + finalize (+ optional fused z2 emit) ----------------
template <int RW, int TIN, int TOFF, bool EMITZ>
__global__ __launch_bounds__(256) void fin_kernel(
    const float* __restrict__ in,
    const unsigned* __restrict__ zq,
    const int* __restrict__ offsets,
    const unsigned* __restrict__ csr,        // 4-B records [src:19 @13][w13 @0]
    const float* __restrict__ wre, const float* __restrict__ bre,
    const float* __restrict__ wrt, const float* __restrict__ brt,
    const float* __restrict__ w2e, const float* __restrict__ b2e,
    const float* __restrict__ w2t, const float* __restrict__ b2t,
    float* __restrict__ outbuf, int nOut,
    unsigned* __restrict__ zq2,
    int n)
{
    __shared__ float sWe[64 * 32];
    __shared__ float sWt[(TIN + 8) * 8];
    __shared__ float sBe[32];
    __shared__ float sBt[8];
    __shared__ float sW2e[32 * 32];
    __shared__ float sW2t[8 * 8];
    __shared__ float sB2e[32];
    __shared__ float sB2t[8];
    for (int i = threadIdx.x; i < 64 * 32; i += 256) sWe[i] = wre[i];
    for (int i = threadIdx.x; i < (TIN + 8) * 8; i += 256) sWt[i] = wrt[i];
    if (threadIdx.x < 32) sBe[threadIdx.x] = bre[threadIdx.x];
    if (threadIdx.x < 8)  sBt[threadIdx.x] = brt[threadIdx.x];
    if (EMITZ) {
        for (int i = threadIdx.x; i < 32 * 32; i += 256) sW2e[i] = w2e[i];
        for (int i = threadIdx.x; i < 8 * 8; i += 256) sW2t[i] = w2t[i];
        if (threadIdx.x < 32) sB2e[threadIdx.x] = b2e[threadIdx.x];
        if (threadIdx.x < 8)  sB2t[threadIdx.x] = b2t[threadIdx.x];
    }
    __syncthreads();

    int node = blockIdx.x * 256 + threadIdx.x;
    if (node >= n) return;

    float acc[40];
    #pragma unroll
    for (int j = 0; j < 40; j++) acc[j] = 0.0f;
    float wsum = 1.0f;

    const float DW = 1.0f / 8191.0f;
    int e0 = offsets[node];
    int e1 = offsets[node + 1];
    int e = e0;
    for (; e + 2 <= e1; e += 2) {
        unsigned pk0 = csr[e];
        unsigned pk1 = csr[e + 1];
        const uint4* p0 = (const uint4*)(zq + (size_t)(pk0 >> 13) * 16);
        const uint4* p1 = (const uint4*)(zq + (size_t)(pk1 >> 13) * 16);
        uint4 A0 = p0[0], B0 = p0[1], C0 = p0[2], D0 = p0[3];
        uint4 A1 = p1[0], B1 = p1[1], C1 = p1[2], D1 = p1[3];
        float w0 = (float)(pk0 & 8191u) * DW;
        float w1 = (float)(pk1 & 8191u) * DW;
        acc_edge(acc, w0, A0, B0, C0, D0);
        acc_edge(acc, w1, A1, B1, C1, D1);
        wsum += w0;
        wsum += w1;
    }
    if (e < e1) {
        unsigned pk = csr[e];
        const uint4* zp = (const uint4*)(zq + (size_t)(pk >> 13) * 16);
        uint4 A = zp[0], B = zp[1], C = zp[2], D = zp[3];
        float w = (float)(pk & 8191u) * DW;
        acc_edge(acc, w, A, B, C, D);
        wsum += w;
    }
    float inv = 1.0f / wsum;
    #pragma unroll
    for (int j = 0; j < 40; j++) acc[j] *= inv;

    float row[RW];
    {
        const float4* rp = (const float4*)(in + (size_t)node * RW);
        #pragma unroll
        for (int q = 0; q < RW / 4; q++) {
            float4 v = rp[q];
            row[4*q] = v.x; row[4*q+1] = v.y; row[4*q+2] = v.z; row[4*q+3] = v.w;
        }
    }

    float h[40];

    {
        float o[32];
        #pragma unroll
        for (int j = 0; j < 32; j++) o[j] = sBe[j];
        #pragma unroll
        for (int i = 0; i < 32; i++) {
            float v = row[i];
            #pragma unroll
            for (int j = 0; j < 32; j++) o[j] = fmaf(v, sWe[i * 32 + j], o[j]);
        }
        #pragma unroll
        for (int i = 0; i < 32; i++) {
            float v = acc[i];
            #pragma unroll
            for (int j = 0; j < 32; j++) o[j] = fmaf(v, sWe[(32 + i) * 32 + j], o[j]);
        }
        #pragma unroll
        for (int j = 0; j < 32; j++) h[j] = relu_(o[j]);
    }
    {
        float ot[8];
        #pragma unroll
        for (int j = 0; j < 8; j++) ot[j] = sBt[j];
        #pragma unroll
        for (int i = 0; i < TIN; i++) {
            float v = row[TOFF + i];
            #pragma unroll
            for (int j = 0; j < 8; j++) ot[j] = fmaf(v, sWt[i * 8 + j], ot[j]);
        }
        #pragma unroll
        for (int i = 0; i < 8; i++) {
            float v = acc[32 + i];
            #pragma unroll
            for (int j = 0; j < 8; j++) ot[j] = fmaf(v, sWt[(TIN + i) * 8 + j], ot[j]);
        }
        #pragma unroll
        for (int j = 0; j < 8; j++) h[32 + j] = relu_(ot[j]);
    }

    if (node < nOut) {
        float4* ov = (float4*)(outbuf + (size_t)node * 40);
        #pragma unroll
        for (int q = 0; q < 10; q++)
            ov[q] = make_float4(h[4*q], h[4*q+1], h[4*q+2], h[4*q+3]);
    }

    if (EMITZ) {
        float z2[40];
        #pragma unroll
        for (int j = 0; j < 32; j++) z2[j] = sB2e[j];
        #pragma unroll
        for (int i = 0; i < 32; i++) {
            float v = h[i];
            #pragma unroll
            for (int j = 0; j < 32; j++) z2[j] = fmaf(v, sW2e[i * 32 + j], z2[j]);
        }
        #pragma unroll
        for (int j = 0; j < 8; j++) z2[32 + j] = sB2t[j];
        #pragma unroll
        for (int i = 0; i < 8; i++) {
            float v = h[32 + i];
            #pragma unroll
            for (int j = 0; j < 8; j++) z2[32 + j] = fmaf(v, sW2t[i * 8 + j], z2[32 + j]);
        }
        unsigned b[40];
        #pragma unroll
        for (int i = 0; i < 40; i++) b[i] = enc12(relu_(z2[i]));
        unsigned wd[16];
        #pragma unroll
        for (int k = 0; k < 5; k++) {
            wd[3*k+0] = b[8*k+0] | (b[8*k+1] << 12) | (b[8*k+2] << 24);
            wd[3*k+1] = (b[8*k+2] >> 8) | (b[8*k+3] << 4) | (b[8*k+4] << 16) | (b[8*k+5] << 28);
            wd[3*k+2] = (b[8*k+5] >> 4) | (b[8*k+6] << 8) | (b[8*k+7] << 20);
        }
        wd[15] = 0;
        uint4* zv = (uint4*)(zq2 + (size_t)node * 16);
        #pragma unroll
        for (int q = 0; q < 4; q++)
            zv[q] = make_uint4(wd[4*q], wd[4*q+1], wd[4*q+2], wd[4*q+3]);
    }
}

// ---------------- loss ----------------

__device__ __forceinline__ void load40(const float* p, float* r) {
    const float4* v = (const float4*)p;
    #pragma unroll
    for (int q = 0; q < 10; q++) {
        float4 t = v[q];
        r[4*q] = t.x; r[4*q+1] = t.y; r[4*q+2] = t.z; r[4*q+3] = t.w;
    }
}

__device__ __forceinline__ float dot40(const float* a, const float* b) {
    float s = 0.0f;
    #pragma unroll
    for (int d = 0; d < 40; d++) s = fmaf(a[d], b[d], s);
    return s;
}

__device__ __forceinline__ void softmax5(const float l[5], float q[5]) {
    float m = l[0];
    #pragma unroll
    for (int c = 1; c < 5; c++) m = fmaxf(m, l[c]);
    float s = 0.0f;
    #pragma unroll
    for (int c = 0; c < 5; c++) { q[c] = expf(l[c] - m); s += q[c]; }
    float inv = 1.0f / s;
    #pragma unroll
    for (int c = 0; c < 5; c++) q[c] *= inv;
}

__device__ __forceinline__ float ent5(const float q[5]) {
    float e = 0.0f;
    #pragma unroll
    for (int c = 0; c < 5; c++) e += q[c] * logf(q[c] + 1e-20f);
    return e;
}

__device__ __forceinline__ float dot5(const float* a, const float* b) {
    float s = 0.0f;
    #pragma unroll
    for (int c = 0; c < 5; c++) s += a[c] * b[c];
    return s;
}

__global__ __launch_bounds__(256) void loss_kernel(
    const float* __restrict__ emb,
    const float* __restrict__ cent,
    const float* __restrict__ cent_t,
    float* __restrict__ out)
{
    __shared__ float sC[5 * 40];
    for (int i = threadIdx.x; i < 200; i += 256) {
        int c = i / 40, d = i % 40;
        sC[i] = (d < 32) ? cent[c * 32 + d] : cent_t[c * 8 + (d - 32)];
    }
    __syncthreads();

    int i = blockIdx.x * 256 + threadIdx.x;
    float contrib = 0.0f;
    if (i < BQ) {
        const float* base = emb + (size_t)i * 200;

        float ctr[40];
        load40(base, ctr);
        float l[5];
        #pragma unroll
        for (int c = 0; c < 5; c++) l[c] = dot40(ctr, sC + c * 40);
        float qc[5];
        softmax5(l, qc);
        float ent = ent5(qc);

        float rowv[40];
        load40(base + 40, rowv);
        float pd = dot40(ctr, rowv);
        #pragma unroll
        for (int c = 0; c < 5; c++) l[c] = dot40(rowv, sC + c * 40);
        float qp[5];
        softmax5(l, qp);
        float cpd = dot5(qc, qp);
        ent += ent5(qp);

        float nd = -1e30f, cnd = -1e30f;
        #pragma unroll
        for (int k = 0; k < 3; k++) {
            load40(base + (2 + k) * 40, rowv);
            nd = fmaxf(nd, dot40(ctr, rowv));
            #pragma unroll
            for (int c = 0; c < 5; c++) l[c] = dot40(rowv, sC + c * 40);
            float qn[5];
            softmax5(l, qn);
            cnd = fmaxf(cnd, dot5(qc, qn));
            ent += ent5(qn);
        }

        float mm  = fmaxf(nd - pd + 1.0f, 0.0f);
        float cmm = fmaxf(cnd - cpd + 1.0f, 0.0f);
        contrib = (mm + cmm) * (1.0f / (float)BQ) + 0.01f * (1.0f / (float)BS) * ent;
    }

    #pragma unroll
    for (int off = 32; off > 0; off >>= 1) contrib += __shfl_down(contrib, off);
    if ((threadIdx.x & 63) == 0) atomicAdd(out, contrib);
}

// ---------------- launch ----------------

extern "C" void kernel_launch(void* const* d_in, const int* in_sizes, int n_in,
                              void* d_out, int out_size, void* d_ws, size_t ws_size,
                              hipStream_t stream) {
    const float* x      = (const float*)d_in[0];
    const float* weight = (const float*)d_in[1];
    const float* e_w1l  = (const float*)d_in[2];
    const float* e_b1l  = (const float*)d_in[3];
    const float* e_w1r  = (const float*)d_in[4];
    const float* e_b1r  = (const float*)d_in[5];
    const float* e_w2l  = (const float*)d_in[6];
    const float* e_b2l  = (const float*)d_in[7];
    const float* e_w2r  = (const float*)d_in[8];
    const float* e_b2r  = (const float*)d_in[9];
    const float* t_w1l  = (const float*)d_in[10];
    const float* t_b1l  = (const float*)d_in[11];
    const float* t_w1r  = (const float*)d_in[12];
    const float* t_b1r  = (const float*)d_in[13];
    const float* t_w2l  = (const float*)d_in[14];
    const float* t_b2l  = (const float*)d_in[15];
    const float* t_w2r  = (const float*)d_in[16];
    const float* t_b2r  = (const float*)d_in[17];
    const float* cent   = (const float*)d_in[18];
    const float* cent_t = (const float*)d_in[19];
    const int*   eidx   = (const int*)d_in[20];

    const int E = in_sizes[20] / 2;
    const int N = in_sizes[0] / 32;
    const int* srcI = eidx;
    const int* dstI = eidx + E;
    float* out = (float*)d_out;

    const int NC = (N + CB - 1) / CB;                    // 489 buckets (1024 nodes)
    const int per = (((E + NWG - 1) / NWG) + 3) & ~3;    // WG slice, multiple of 4

    char* p = (char*)d_ws;
    auto alloc = [&](size_t bytes) -> char* {
        char* r = p;
        p += (bytes + 255) & ~(size_t)255;
        return r;
    };
    char* regionA = alloc((size_t)E * 8);                // tmp (64 MB) / zq1 (32 MB)
    ull*  tmp     = (ull*)regionA;
    unsigned* zq1 = (unsigned*)regionA;
    unsigned* zq2 = (unsigned*)alloc((size_t)N * 64);    // 32 MB
    float* hcat   = (float*)alloc((size_t)BS * 40 * 4);  // 16 MB
    float* emb    = (float*)alloc((size_t)BS * 40 * 4);  // 16 MB
    unsigned* csr = (unsigned*)alloc((size_t)E * 4);     // 32 MB
    int*   offsets= (int*)alloc((size_t)(N + 1) * 4);
    int*   hist2D = (int*)alloc((size_t)NC * NWG * 4);   // 1 MB
    int*   wgbase = (int*)alloc((size_t)NC * NWG * 4);   // 1 MB
    int*   bucketTot  = (int*)alloc((size_t)NC * 4);
    int*   bucketBase = (int*)alloc((size_t)NC * 4);
    (void)ws_size;

    hipMemsetAsync(d_out, 0, sizeof(float), stream);

    // binning
    hist_kernel<<<NWG, 1024, 0, stream>>>(dstI, E, NC, per, hist2D);
    reduce_kernel<<<NC, 256, 0, stream>>>(hist2D, bucketTot);
    scanTot_kernel<<<1, 512, 0, stream>>>(bucketTot, NC, bucketBase);
    scanB_kernel<<<NC, NWG, 0, stream>>>(hist2D, bucketBase, wgbase);
    fillA_kernel<<<NWG, 1024, 0, stream>>>(srcI, dstI, weight, E, NC, per, wgbase, tmp);
    fillA2B_kernel<<<NC, 1024, (size_t)CAP * 4, stream>>>(tmp, wgbase, NC, N, E, csr, offsets);

    const int nb = (N + 255) / 256;
    z1_kernel<<<nb, 256, 0, stream>>>(x, e_w1l, e_b1l, t_w1l, t_b1l, zq1, N);
    fin_kernel<32, 32, 0, true><<<nb, 256, 0, stream>>>(
        x, zq1, offsets, csr,
        e_w1r, e_b1r, t_w1r, t_b1r,
        e_w2l, e_b2l, t_w2l, t_b2l,
        hcat, BS, zq2, N);
    const int nb2 = (BS + 255) / 256;
    fin_kernel<40, 8, 32, false><<<nb2, 256, 0, stream>>>(
        hcat, zq2, offsets, csr,
        e_w2r, e_b2r, t_w2r, t_b2r,
        nullptr, nullptr, nullptr, nullptr,
        emb, BS, nullptr, BS);

    loss_kernel<<<(BQ + 255) / 256, 256, 0, stream>>>(emb, cent, cent_t, out);
}

// Round 18
// 462.613 us; speedup vs baseline: 1.2219x; 1.0949x over previous
//
#include <hip/hip_runtime.h>

#define BS 100000
#define BQ 20000          // BS / 5
#define NWG 512           // workgroups in hist/fillA partition (1024 thr each)
#define CB  1024          // nodes per coarse bucket
#define NCMAX 512
#define CAP 17408         // staged 4-B records in fillA2B
#define RING_D 16         // 2-line ring per bucket in fillA

typedef unsigned long long ull;

__device__ __forceinline__ float relu_(float v) { return fmaxf(v, 0.0f); }

// ---- 12-bit unsigned float codec (e5|m7, bias 112) ----
__device__ __forceinline__ unsigned enc12(float f) {
    unsigned u = __float_as_uint(f);
    if (u < 0x38000000u) return 0u;
    unsigned r = u - 0x38000000u;
    unsigned b = (r + 0x7FFFu + ((r >> 16) & 1u)) >> 16;
    return (b > 0xFFFu) ? 0xFFFu : b;
}
__device__ __forceinline__ float dec12(unsigned b) {
    return __uint_as_float((b << 16) + 0x38000000u);
}

// ================= binning =================
// tmp record: [valid:1 @63][dst&1023:10 @51][src:19 @32][wbits:32 @0]
// streams padded to 8-record (64 B) multiples; pad records have valid=0
// csr record (4 B): [src:19 @13][w_fix13 @0]  (dense, actual positions)

__global__ __launch_bounds__(1024) void hist_kernel(
    const int* __restrict__ dst, int E, int NC, int per, int* __restrict__ hist2D)
{
    __shared__ int lc[NCMAX];
    int t = threadIdx.x, g = blockIdx.x;
    for (int i = t; i < NC; i += 1024) lc[i] = 0;
    __syncthreads();
    int lo = g * per, hi = min(lo + per, E);
    if (lo < hi) {
        int nq = (hi - lo) >> 2;
        const int4* dst4 = (const int4*)(dst + lo);
        for (int q = t; q < nq; q += 1024) {
            int4 d = dst4[q];
            atomicAdd(&lc[d.x >> 10], 1);
            atomicAdd(&lc[d.y >> 10], 1);
            atomicAdd(&lc[d.z >> 10], 1);
            atomicAdd(&lc[d.w >> 10], 1);
        }
        for (int i = lo + (nq << 2) + t; i < hi; i += 1024)
            atomicAdd(&lc[dst[i] >> 10], 1);
    }
    __syncthreads();
    for (int b = t; b < NC; b += 1024) hist2D[(size_t)b * NWG + g] = lc[b];
}

// per-bucket padded and actual totals
__global__ __launch_bounds__(256) void reduce_kernel(
    const int* __restrict__ hist2D, int* __restrict__ bucketTotPad,
    int* __restrict__ bucketTotAct)
{
    __shared__ int sp[256];
    __shared__ int sa[256];
    int b = blockIdx.x, t = threadIdx.x;
    int sumP = 0, sumA = 0;
    for (int g = t; g < NWG; g += 256) {
        int c = hist2D[(size_t)b * NWG + g];
        sumA += c;
        sumP += (c + 7) & ~7;
    }
    sp[t] = sumP; sa[t] = sumA;
    __syncthreads();
    for (int d = 128; d > 0; d >>= 1) {
        if (t < d) { sp[t] += sp[t + d]; sa[t] += sa[t + d]; }
        __syncthreads();
    }
    if (t == 0) { bucketTotPad[b] = sp[0]; bucketTotAct[b] = sa[0]; }
}

// exclusive scans of padded (with grand total at [NC]) and actual totals
__global__ __launch_bounds__(512) void scanTot_kernel(
    const int* __restrict__ bucketTotPad, const int* __restrict__ bucketTotAct,
    int NC, int* __restrict__ bucketBasePad, int* __restrict__ bucketBaseAct)
{
    __shared__ int s[512];
    int t = threadIdx.x;
    int v = (t < NC) ? bucketTotPad[t] : 0;
    s[t] = v;
    __syncthreads();
    for (int d = 1; d < 512; d <<= 1) {
        int x = (t >= d) ? s[t - d] : 0;
        __syncthreads();
        s[t] += x;
        __syncthreads();
    }
    if (t < NC) bucketBasePad[t] = s[t] - v;
    if (t == NC - 1) bucketBasePad[NC] = s[t];
    __syncthreads();
    int va = (t < NC) ? bucketTotAct[t] : 0;
    s[t] = va;
    __syncthreads();
    for (int d = 1; d < 512; d <<= 1) {
        int x = (t >= d) ? s[t - d] : 0;
        __syncthreads();
        s[t] += x;
        __syncthreads();
    }
    if (t < NC) bucketBaseAct[t] = s[t] - va;
}

// per-bucket scan over padded per-WG counts -> wgbase (padded space, 8-aligned)
__global__ __launch_bounds__(NWG) void scanB_kernel(
    const int* __restrict__ hist2D, const int* __restrict__ bucketBasePad,
    int* __restrict__ wgbase)
{
    __shared__ int s[NWG];
    int b = blockIdx.x, g = threadIdx.x;
    int v = (hist2D[(size_t)b * NWG + g] + 7) & ~7;
    s[g] = v;
    __syncthreads();
    for (int d = 1; d < NWG; d <<= 1) {
        int x = (g >= d) ? s[g - d] : 0;
        __syncthreads();
        s[g] += x;
        __syncthreads();
    }
    wgbase[(size_t)b * NWG + g] = bucketBasePad[b] + s[g] - v;
}

// line-staged fillA: LDS ring per bucket, flush complete 64-B lines.
__global__ __launch_bounds__(1024) void fillA_kernel(
    const int* __restrict__ src, const int* __restrict__ dst,
    const float* __restrict__ w, int E, int NC, int per,
    const int* __restrict__ wgbase, ull* __restrict__ tmp)
{
    extern __shared__ ull ring[];          // NC * RING_D
    __shared__ int cur[NCMAX];             // absolute cursor
    __shared__ int flq[NCMAX];             // next absolute line to flush
    __shared__ unsigned vmask[NCMAX];
    int t = threadIdx.x, g = blockIdx.x;
    for (int i = t; i < NC; i += 1024) {
        int base = wgbase[(size_t)i * NWG + g];
        cur[i] = base;
        flq[i] = base >> 3;
        vmask[i] = 0u;
    }
    __syncthreads();

    int lo = g * per, hi = min(lo + per, E);
    int groups = (per + 4095) >> 12;
    for (int gi = 0; gi < groups; gi++) {
        int eb = lo + (gi << 12) + (t << 2);
        int4 d4 = make_int4(0, 0, 0, 0), s4 = make_int4(0, 0, 0, 0);
        float4 w4 = make_float4(0, 0, 0, 0);
        if (eb + 4 <= hi) {
            d4 = *(const int4*)(dst + eb);
            s4 = *(const int4*)(src + eb);
            w4 = *(const float4*)(w + eb);
        } else if (eb < hi) {
            int m = hi - eb;
            if (m > 0) { d4.x = dst[eb];     s4.x = src[eb];     w4.x = w[eb]; }
            if (m > 1) { d4.y = dst[eb + 1]; s4.y = src[eb + 1]; w4.y = w[eb + 1]; }
            if (m > 2) { d4.z = dst[eb + 2]; s4.z = src[eb + 2]; w4.z = w[eb + 2]; }
        }
        #pragma unroll
        for (int k = 0; k < 4; k++) {
            if (eb + k < hi) {
                int d = (k == 0) ? d4.x : (k == 1) ? d4.y : (k == 2) ? d4.z : d4.w;
                int s = (k == 0) ? s4.x : (k == 1) ? s4.y : (k == 2) ? s4.z : s4.w;
                float wv = (k == 0) ? w4.x : (k == 1) ? w4.y : (k == 2) ? w4.z : w4.w;
                int b = d >> 10;
                ull rec = (1ull << 63)
                        | ((ull)(unsigned)(d & (CB - 1)) << 51)
                        | ((ull)(unsigned)s << 32)
                        | (ull)__float_as_uint(wv);
                int pos = atomicAdd(&cur[b], 1);
                if ((pos >> 3) < flq[b] + 2) {
                    int slot = pos & 15;
                    ring[b * RING_D + slot] = rec;
                    atomicOr(&vmask[b], 1u << slot);
                } else {
                    tmp[pos] = rec;        // rare overflow: direct write
                }
            }
            __syncthreads();
            if (t < NC) {
                int bb = t;
                int endL = cur[bb] >> 3;
                int L = flq[bb];
                unsigned vm = vmask[bb];
                while (L < endL) {
                    int half = (L & 1) << 3;
                    unsigned m8 = (vm >> half) & 0xFFu;
                    ull* dp = tmp + ((size_t)L << 3);
                    const ull* rp = ring + bb * RING_D + half;
                    if (m8 == 0xFFu) {
                        uint4* d16 = (uint4*)dp;
                        const uint4* r16 = (const uint4*)rp;
                        d16[0] = r16[0]; d16[1] = r16[1];
                        d16[2] = r16[2]; d16[3] = r16[3];
                    } else if (m8) {
                        #pragma unroll
                        for (int j = 0; j < 8; j++)
                            if (m8 & (1u << j)) dp[j] = rp[j];
                    }
                    vm &= ~(0xFFu << half);
                    L++;
                }
                vmask[bb] = vm;
                flq[bb] = L;
            }
            __syncthreads();
        }
    }

    // epilogue: pad each stream to a line boundary with invalid recs, flush rest
    if (t < NC) {
        int bb = t;
        int c = cur[bb];
        int padded = (c + 7) & ~7;
        unsigned vm = vmask[bb];
        for (int p = c; p < padded; p++) {
            int slot = p & 15;
            ring[bb * RING_D + slot] = 0ull;   // valid=0
            vm |= 1u << slot;
        }
        int endL = padded >> 3;
        int L = flq[bb];
        while (L < endL) {
            int half = (L & 1) << 3;
            unsigned m8 = (vm >> half) & 0xFFu;
            ull* dp = tmp + ((size_t)L << 3);
            const ull* rp = ring + bb * RING_D + half;
            if (m8 == 0xFFu) {
                uint4* d16 = (uint4*)dp;
                const uint4* r16 = (const uint4*)rp;
                d16[0] = r16[0]; d16[1] = r16[1];
                d16[2] = r16[2]; d16[3] = r16[3];
            } else if (m8) {
                #pragma unroll
                for (int j = 0; j < 8; j++)
                    if (m8 & (1u << j)) dp[j] = rp[j];
            }
            vm &= ~(0xFFu << half);
            L++;
        }
    }
}

// one WG (1024 thr) per bucket: count valid -> scan(1024) -> LDS-staged reorder ->
// sequential dense csr write at actual base
__global__ __launch_bounds__(1024) void fillA2B_kernel(
    const ull* __restrict__ tmp, const int* __restrict__ wgbase,
    const int* __restrict__ bucketBasePad, const int* __restrict__ bucketBaseAct,
    int NC, int N, int E,
    unsigned* __restrict__ csr, int* __restrict__ offsets)
{
    __shared__ int cnt[CB];
    __shared__ int ssum[1024];
    extern __shared__ unsigned recs[];   // CAP 4-B records
    int b = blockIdx.x, t = threadIdx.x;
    int lo = wgbase[(size_t)b * NWG];
    int hi = (b == NC - 1) ? bucketBasePad[NC] : wgbase[(size_t)(b + 1) * NWG];
    int actLo = bucketBaseAct[b];

    cnt[t] = 0;
    __syncthreads();
    for (int e = lo + t; e < hi; e += 1024) {
        ull rec = tmp[e];
        if (rec >> 63) atomicAdd(&cnt[(int)((rec >> 51) & (CB - 1))], 1);
    }
    __syncthreads();

    int v = cnt[t];
    ssum[t] = v;
    __syncthreads();
    for (int d = 1; d < 1024; d <<= 1) {
        int x = (t >= d) ? ssum[t - d] : 0;
        __syncthreads();
        ssum[t] += x;
        __syncthreads();
    }
    int excl = ssum[t] - v;
    int Mact = ssum[1023];

    int node = b * CB + t;
    if (node < N) offsets[node] = actLo + excl;
    if (b == NC - 1 && t == 0) offsets[N] = E;
    __syncthreads();
    cnt[t] = excl;
    __syncthreads();

    if (Mact <= CAP) {
        for (int e = lo + t; e < hi; e += 1024) {
            ull rec = tmp[e];
            if (!(rec >> 63)) continue;
            int dl = (int)((rec >> 51) & (CB - 1));
            int pos = atomicAdd(&cnt[dl], 1);
            float w = __uint_as_float((unsigned int)(rec & 0xFFFFFFFFull));
            unsigned wq = (unsigned)fmaf(w, 8191.0f, 0.5f);
            unsigned sidx = (unsigned)((rec >> 32) & 0x7FFFFull);
            recs[pos] = (sidx << 13) | wq;
        }
        __syncthreads();
        for (int i = t; i < Mact; i += 1024)
            csr[actLo + i] = recs[i];
    } else {
        for (int e = lo + t; e < hi; e += 1024) {
            ull rec = tmp[e];
            if (!(rec >> 63)) continue;
            int dl = (int)((rec >> 51) & (CB - 1));
            int pos = atomicAdd(&cnt[dl], 1);
            float w = __uint_as_float((unsigned int)(rec & 0xFFFFFFFFull));
            unsigned wq = (unsigned)fmaf(w, 8191.0f, 0.5f);
            unsigned sidx = (unsigned)((rec >> 32) & 0x7FFFFull);
            csr[actLo + pos] = (sidx << 13) | wq;
        }
    }
}

// ---------------- z1 = relu(x @ Wl + bl) -> 12-bit packed rows ----------------
__global__ __launch_bounds__(256) void z1_kernel(
    const float* __restrict__ in,
    const float* __restrict__ we, const float* __restrict__ be,
    const float* __restrict__ wt, const float* __restrict__ bt,
    unsigned* __restrict__ zq, int n)
{
    __shared__ float sWe[32 * 32];
    __shared__ float sWt[32 * 8];
    __shared__ float sBe[32];
    __shared__ float sBt[8];
    for (int i = threadIdx.x; i < 32 * 32; i += 256) sWe[i] = we[i];
    for (int i = threadIdx.x; i < 32 * 8; i += 256) sWt[i] = wt[i];
    if (threadIdx.x < 32) sBe[threadIdx.x] = be[threadIdx.x];
    if (threadIdx.x < 8)  sBt[threadIdx.x] = bt[threadIdx.x];
    __syncthreads();

    int node = blockIdx.x * 256 + threadIdx.x;
    if (node >= n) return;

    float row[32];
    {
        const float4* rp = (const float4*)(in + (size_t)node * 32);
        #pragma unroll
        for (int q = 0; q < 8; q++) {
            float4 v = rp[q];
            row[4*q] = v.x; row[4*q+1] = v.y; row[4*q+2] = v.z; row[4*q+3] = v.w;
        }
    }

    float o[40];
    #pragma unroll
    for (int j = 0; j < 32; j++) o[j] = sBe[j];
    #pragma unroll
    for (int i = 0; i < 32; i++) {
        float v = row[i];
        #pragma unroll
        for (int j = 0; j < 32; j++) o[j] = fmaf(v, sWe[i * 32 + j], o[j]);
    }
    #pragma unroll
    for (int j = 0; j < 8; j++) o[32 + j] = sBt[j];
    #pragma unroll
    for (int i = 0; i < 32; i++) {
        float v = row[i];
        #pragma unroll
        for (int j = 0; j < 8; j++) o[32 + j] = fmaf(v, sWt[i * 8 + j], o[32 + j]);
    }

    unsigned b[40];
    #pragma unroll
    for (int i = 0; i < 40; i++) b[i] = enc12(relu_(o[i]));
    unsigned wd[16];
    #pragma unroll
    for (int k = 0; k < 5; k++) {
        wd[3*k+0] = b[8*k+0] | (b[8*k+1] << 12) | (b[8*k+2] << 24);
        wd[3*k+1] = (b[8*k+2] >> 8) | (b[8*k+3] << 4) | (b[8*k+4] << 16) | (b[8*k+5] << 28);
        wd[3*k+2] = (b[8*k+5] >> 4) | (b[8*k+6] << 8) | (b[8*k+7] << 20);
    }
    wd[15] = 0;
    uint4* zv = (uint4*)(zq + (size_t)node * 16);
    #pragma unroll
    for (int q = 0; q < 4; q++)
        zv[q] = make_uint4(wd[4*q], wd[4*q+1], wd[4*q+2], wd[4*q+3]);
}

// ---------------- decode+accumulate one edge ----------------
__device__ __forceinline__ void acc_edge(float* acc, float w,
    const uint4& A, const uint4& B, const uint4& C, const uint4& D)
{
    unsigned wds[15] = {A.x, A.y, A.z, A.w, B.x, B.y, B.z, B.w,
                        C.x, C.y, C.z, C.w, D.x, D.y, D.z};
    #pragma unroll
    for (int k = 0; k < 5; k++) {
        unsigned xw = wds[3*k+0], yw = wds[3*k+1], zw = wds[3*k+2];
        acc[8*k+0] = fmaf(w, dec12(xw & 0xFFFu),                       acc[8*k+0]);
        acc[8*k+1] = fmaf(w, dec12((xw >> 12) & 0xFFFu),               acc[8*k+1]);
        acc[8*k+2] = fmaf(w, dec12(((xw >> 24) | (yw << 8)) & 0xFFFu), acc[8*k+2]);
        acc[8*k+3] = fmaf(w, dec12((yw >> 4) & 0xFFFu),                acc[8*k+3]);
        acc[8*k+4] = fmaf(w, dec12((yw >> 16) & 0xFFFu),               acc[8*k+4]);
        acc[8*k+5] = fmaf(w, dec12(((yw >> 28) | (zw << 4)) & 0xFFFu), acc[8*k+5]);
        acc[8*k+6] = fmaf(w, dec12((zw >> 8) & 0xFFFu),                acc[8*k+6]);
        acc[8*k+7] = fmaf(w, dec12((zw >> 20) & 0xFFFu),               acc[8*k+7]);
    }
}

// ---------------- fused aggregate + finalize (+ optional fused z2 emit) ----------------
template <int RW, int TIN, int TOFF, bool EMITZ>
__global__ __launch_bounds__(256) void fin_kernel(
    const float* __restrict__ in,
    const unsigned* __restrict__ zq,
    const int* __restrict__ offsets,
    const unsigned* __restrict__ csr,        // 4-B records [src:19 @13][w13 @0]
    const float* __restrict__ wre, const float* __restrict__ bre,
    const float* __restrict__ wrt, const float* __restrict__ brt,
    const float* __restrict__ w2e, const float* __restrict__ b2e,
    const float* __restrict__ w2t, const float* __restrict__ b2t,
    float* __restrict__ outbuf, int nOut,
    unsigned* __restrict__ zq2,
    int n)
{
    __shared__ float sWe[64 * 32];
    __shared__ float sWt[(TIN + 8) * 8];
    __shared__ float sBe[32];
    __shared__ float sBt[8];
    __shared__ float sW2e[32 * 32];
    __shared__ float sW2t[8 * 8];
    __shared__ float sB2e[32];
    __shared__ float sB2t[8];
    for (int i = threadIdx.x; i < 64 * 32; i += 256) sWe[i] = wre[i];
    for (int i = threadIdx.x; i < (TIN + 8) * 8; i += 256) sWt[i] = wrt[i];
    if (threadIdx.x < 32) sBe[threadIdx.x] = bre[threadIdx.x];
    if (threadIdx.x < 8)  sBt[threadIdx.x] = brt[threadIdx.x];
    if (EMITZ) {
        for (int i = threadIdx.x; i < 32 * 32; i += 256) sW2e[i] = w2e[i];
        for (int i = threadIdx.x; i < 8 * 8; i += 256) sW2t[i] = w2t[i];
        if (threadIdx.x < 32) sB2e[threadIdx.x] = b2e[threadIdx.x];
        if (threadIdx.x < 8)  sB2t[threadIdx.x] = b2t[threadIdx.x];
    }
    __syncthreads();

    int node = blockIdx.x * 256 + threadIdx.x;
    if (node >= n) return;

    float acc[40];
    #pragma unroll
    for (int j = 0; j < 40; j++) acc[j] = 0.0f;
    float wsum = 1.0f;

    const float DW = 1.0f / 8191.0f;
    int e0 = offsets[node];
    int e1 = offsets[node + 1];
    int e = e0;
    for (; e + 2 <= e1; e += 2) {
        unsigned pk0 = csr[e];
        unsigned pk1 = csr[e + 1];
        const uint4* p0 = (const uint4*)(zq + (size_t)(pk0 >> 13) * 16);
        const uint4* p1 = (const uint4*)(zq + (size_t)(pk1 >> 13) * 16);
        uint4 A0 = p0[0], B0 = p0[1], C0 = p0[2], D0 = p0[3];
        uint4 A1 = p1[0], B1 = p1[1], C1 = p1[2], D1 = p1[3];
        float w0 = (float)(pk0 & 8191u) * DW;
        float w1 = (float)(pk1 & 8191u) * DW;
        acc_edge(acc, w0, A0, B0, C0, D0);
        acc_edge(acc, w1, A1, B1, C1, D1);
        wsum += w0;
        wsum += w1;
    }
    if (e < e1) {
        unsigned pk = csr[e];
        const uint4* zp = (const uint4*)(zq + (size_t)(pk >> 13) * 16);
        uint4 A = zp[0], B = zp[1], C = zp[2], D = zp[3];
        float w = (float)(pk & 8191u) * DW;
        acc_edge(acc, w, A, B, C, D);
        wsum += w;
    }
    float inv = 1.0f / wsum;
    #pragma unroll
    for (int j = 0; j < 40; j++) acc[j] *= inv;

    float row[RW];
    {
        const float4* rp = (const float4*)(in + (size_t)node * RW);
        #pragma unroll
        for (int q = 0; q < RW / 4; q++) {
            float4 v = rp[q];
            row[4*q] = v.x; row[4*q+1] = v.y; row[4*q+2] = v.z; row[4*q+3] = v.w;
        }
    }

    float h[40];

    {
        float o[32];
        #pragma unroll
        for (int j = 0; j < 32; j++) o[j] = sBe[j];
        #pragma unroll
        for (int i = 0; i < 32; i++) {
            float v = row[i];
            #pragma unroll
            for (int j = 0; j < 32; j++) o[j] = fmaf(v, sWe[i * 32 + j], o[j]);
        }
        #pragma unroll
        for (int i = 0; i < 32; i++) {
            float v = acc[i];
            #pragma unroll
            for (int j = 0; j < 32; j++) o[j] = fmaf(v, sWe[(32 + i) * 32 + j], o[j]);
        }
        #pragma unroll
        for (int j = 0; j < 32; j++) h[j] = relu_(o[j]);
    }
    {
        float ot[8];
        #pragma unroll
        for (int j = 0; j < 8; j++) ot[j] = sBt[j];
        #pragma unroll
        for (int i = 0; i < TIN; i++) {
            float v = row[TOFF + i];
            #pragma unroll
            for (int j = 0; j < 8; j++) ot[j] = fmaf(v, sWt[i * 8 + j], ot[j]);
        }
        #pragma unroll
        for (int i = 0; i < 8; i++) {
            float v = acc[32 + i];
            #pragma unroll
            for (int j = 0; j < 8; j++) ot[j] = fmaf(v, sWt[(TIN + i) * 8 + j], ot[j]);
        }
        #pragma unroll
        for (int j = 0; j < 8; j++) h[32 + j] = relu_(ot[j]);
    }

    if (node < nOut) {
        float4* ov = (float4*)(outbuf + (size_t)node * 40);
        #pragma unroll
        for (int q = 0; q < 10; q++)
            ov[q] = make_float4(h[4*q], h[4*q+1], h[4*q+2], h[4*q+3]);
    }

    if (EMITZ) {
        float z2[40];
        #pragma unroll
        for (int j = 0; j < 32; j++) z2[j] = sB2e[j];
        #pragma unroll
        for (int i = 0; i < 32; i++) {
            float v = h[i];
            #pragma unroll
            for (int j = 0; j < 32; j++) z2[j] = fmaf(v, sW2e[i * 32 + j], z2[j]);
        }
        #pragma unroll
        for (int j = 0; j < 8; j++) z2[32 + j] = sB2t[j];
        #pragma unroll
        for (int i = 0; i < 8; i++) {
            float v = h[32 + i];
            #pragma unroll
            for (int j = 0; j < 8; j++) z2[32 + j] = fmaf(v, sW2t[i * 8 + j], z2[32 + j]);
        }
        unsigned b[40];
        #pragma unroll
        for (int i = 0; i < 40; i++) b[i] = enc12(relu_(z2[i]));
        unsigned wd[16];
        #pragma unroll
        for (int k = 0; k < 5; k++) {
            wd[3*k+0] = b[8*k+0] | (b[8*k+1] << 12) | (b[8*k+2] << 24);
            wd[3*k+1] = (b[8*k+2] >> 8) | (b[8*k+3] << 4) | (b[8*k+4] << 16) | (b[8*k+5] << 28);
            wd[3*k+2] = (b[8*k+5] >> 4) | (b[8*k+6] << 8) | (b[8*k+7] << 20);
        }
        wd[15] = 0;
        uint4* zv = (uint4*)(zq2 + (size_t)node * 16);
        #pragma unroll
        for (int q = 0; q < 4; q++)
            zv[q] = make_uint4(wd[4*q], wd[4*q+1], wd[4*q+2], wd[4*q+3]);
    }
}

// ---------------- loss ----------------

__device__ __forceinline__ void load40(const float* p, float* r) {
    const float4* v = (const float4*)p;
    #pragma unroll
    for (int q = 0; q < 10; q++) {
        float4 t = v[q];
        r[4*q] = t.x; r[4*q+1] = t.y; r[4*q+2] = t.z; r[4*q+3] = t.w;
    }
}

__device__ __forceinline__ float dot40(const float* a, const float* b) {
    float s = 0.0f;
    #pragma unroll
    for (int d = 0; d < 40; d++) s = fmaf(a[d], b[d], s);
    return s;
}

__device__ __forceinline__ void softmax5(const float l[5], float q[5]) {
    float m = l[0];
    #pragma unroll
    for (int c = 1; c < 5; c++) m = fmaxf(m, l[c]);
    float s = 0.0f;
    #pragma unroll
    for (int c = 0; c < 5; c++) { q[c] = expf(l[c] - m); s += q[c]; }
    float inv = 1.0f / s;
    #pragma unroll
    for (int c = 0; c < 5; c++) q[c] *= inv;
}

__device__ __forceinline__ float ent5(const float q[5]) {
    float e = 0.0f;
    #pragma unroll
    for (int c = 0; c < 5; c++) e += q[c] * logf(q[c] + 1e-20f);
    return e;
}

__device__ __forceinline__ float dot5(const float* a, const float* b) {
    float s = 0.0f;
    #pragma unroll
    for (int c = 0; c < 5; c++) s += a[c] * b[c];
    return s;
}

__global__ __launch_bounds__(256) void loss_kernel(
    const float* __restrict__ emb,
    const float* __restrict__ cent,
    const float* __restrict__ cent_t,
    float* __restrict__ out)
{
    __shared__ float sC[5 * 40];
    for (int i = threadIdx.x; i < 200; i += 256) {
        int c = i / 40, d = i % 40;
        sC[i] = (d < 32) ? cent[c * 32 + d] : cent_t[c * 8 + (d - 32)];
    }
    __syncthreads();

    int i = blockIdx.x * 256 + threadIdx.x;
    float contrib = 0.0f;
    if (i < BQ) {
        const float* base = emb + (size_t)i * 200;

        float ctr[40];
        load40(base, ctr);
        float l[5];
        #pragma unroll
        for (int c = 0; c < 5; c++) l[c] = dot40(ctr, sC + c * 40);
        float qc[5];
        softmax5(l, qc);
        float ent = ent5(qc);

        float rowv[40];
        load40(base + 40, rowv);
        float pd = dot40(ctr, rowv);
        #pragma unroll
        for (int c = 0; c < 5; c++) l[c] = dot40(rowv, sC + c * 40);
        float qp[5];
        softmax5(l, qp);
        float cpd = dot5(qc, qp);
        ent += ent5(qp);

        float nd = -1e30f, cnd = -1e30f;
        #pragma unroll
        for (int k = 0; k < 3; k++) {
            load40(base + (2 + k) * 40, rowv);
            nd = fmaxf(nd, dot40(ctr, rowv));
            #pragma unroll
            for (int c = 0; c < 5; c++) l[c] = dot40(rowv, sC + c * 40);
            float qn[5];
            softmax5(l, qn);
            cnd = fmaxf(cnd, dot5(qc, qn));
            ent += ent5(qn);
        }

        float mm  = fmaxf(nd - pd + 1.0f, 0.0f);
        float cmm = fmaxf(cnd - cpd + 1.0f, 0.0f);
        contrib = (mm + cmm) * (1.0f / (float)BQ) + 0.01f * (1.0f / (float)BS) * ent;
    }

    #pragma unroll
    for (int off = 32; off > 0; off >>= 1) contrib += __shfl_down(contrib, off);
    if ((threadIdx.x & 63) == 0) atomicAdd(out, contrib);
}

// ---------------- launch ----------------

extern "C" void kernel_launch(void* const* d_in, const int* in_sizes, int n_in,
                              void* d_out, int out_size, void* d_ws, size_t ws_size,
                              hipStream_t stream) {
    const float* x      = (const float*)d_in[0];
    const float* weight = (const float*)d_in[1];
    const float* e_w1l  = (const float*)d_in[2];
    const float* e_b1l  = (const float*)d_in[3];
    const float* e_w1r  = (const float*)d_in[4];
    const float* e_b1r  = (const float*)d_in[5];
    const float* e_w2l  = (const float*)d_in[6];
    const float* e_b2l  = (const float*)d_in[7];
    const float* e_w2r  = (const float*)d_in[8];
    const float* e_b2r  = (const float*)d_in[9];
    const float* t_w1l  = (const float*)d_in[10];
    const float* t_b1l  = (const float*)d_in[11];
    const float* t_w1r  = (const float*)d_in[12];
    const float* t_b1r  = (const float*)d_in[13];
    const float* t_w2l  = (const float*)d_in[14];
    const float* t_b2l  = (const float*)d_in[15];
    const float* t_w2r  = (const float*)d_in[16];
    const float* t_b2r  = (const float*)d_in[17];
    const float* cent   = (const float*)d_in[18];
    const float* cent_t = (const float*)d_in[19];
    const int*   eidx   = (const int*)d_in[20];

    const int E = in_sizes[20] / 2;
    const int N = in_sizes[0] / 32;
    const int* srcI = eidx;
    const int* dstI = eidx + E;
    float* out = (float*)d_out;

    const int NC = (N + CB - 1) / CB;                    // 489 buckets (1024 nodes)
    const int per = (((E + NWG - 1) / NWG) + 3) & ~3;    // WG slice, multiple of 4
    const size_t tmpRecs = (size_t)E + (size_t)NC * NWG * 8;   // padded streams

    char* p = (char*)d_ws;
    auto alloc = [&](size_t bytes) -> char* {
        char* r = p;
        p += (bytes + 255) & ~(size_t)255;
        return r;
    };
    char* regionA = alloc(tmpRecs * 8);                  // tmp (~80 MB) / zq1 (32 MB)
    ull*  tmp     = (ull*)regionA;
    unsigned* zq1 = (unsigned*)regionA;
    unsigned* zq2 = (unsigned*)alloc((size_t)N * 64);    // 32 MB
    float* hcat   = (float*)alloc((size_t)BS * 40 * 4);  // 16 MB
    float* emb    = (float*)alloc((size_t)BS * 40 * 4);  // 16 MB
    unsigned* csr = (unsigned*)alloc((size_t)E * 4);     // 32 MB
    int*   offsets= (int*)alloc((size_t)(N + 1) * 4);
    int*   hist2D = (int*)alloc((size_t)NC * NWG * 4);   // 1 MB
    int*   wgbase = (int*)alloc((size_t)NC * NWG * 4);   // 1 MB
    int*   bucketTotPad  = (int*)alloc((size_t)NC * 4);
    int*   bucketTotAct  = (int*)alloc((size_t)NC * 4);
    int*   bucketBasePad = (int*)alloc((size_t)(NC + 1) * 4);
    int*   bucketBaseAct = (int*)alloc((size_t)NC * 4);
    (void)ws_size;

    hipMemsetAsync(d_out, 0, sizeof(float), stream);

    // binning
    hist_kernel<<<NWG, 1024, 0, stream>>>(dstI, E, NC, per, hist2D);
    reduce_kernel<<<NC, 256, 0, stream>>>(hist2D, bucketTotPad, bucketTotAct);
    scanTot_kernel<<<1, 512, 0, stream>>>(bucketTotPad, bucketTotAct, NC,
                                          bucketBasePad, bucketBaseAct);
    scanB_kernel<<<NC, NWG, 0, stream>>>(hist2D, bucketBasePad, wgbase);
    fillA_kernel<<<NWG, 1024, (size_t)NC * RING_D * 8, stream>>>(
        srcI, dstI, weight, E, NC, per, wgbase, tmp);
    fillA2B_kernel<<<NC, 1024, (size_t)CAP * 4, stream>>>(
        tmp, wgbase, bucketBasePad, bucketBaseAct, NC, N, E, csr, offsets);

    const int nb = (N + 255) / 256;
    z1_kernel<<<nb, 256, 0, stream>>>(x, e_w1l, e_b1l, t_w1l, t_b1l, zq1, N);
    fin_kernel<32, 32, 0, true><<<nb, 256, 0, stream>>>(
        x, zq1, offsets, csr,
        e_w1r, e_b1r, t_w1r, t_b1r,
        e_w2l, e_b2l, t_w2l, t_b2l,
        hcat, BS, zq2, N);
    const int nb2 = (BS + 255) / 256;
    fin_kernel<40, 8, 32, false><<<nb2, 256, 0, stream>>>(
        hcat, zq2, offsets, csr,
        e_w2r, e_b2r, t_w2r, t_b2r,
        nullptr, nullptr, nullptr, nullptr,
        emb, BS, nullptr, BS);

    loss_kernel<<<(BQ + 255) / 256, 256, 0, stream>>>(emb, cent, cent_t, out);
}